// Round 1
// baseline (821.009 us; speedup 1.0000x reference)
//
#include <hip/hip_runtime.h>
#include <stdint.h>

// EncoderLayer on MI355X (gfx950), bf16 MFMA pipeline.
// B=4, S=2048, HID=1024, HEADS=16, HD=64, PF=4096. M = B*S = 8192.

typedef __bf16 bf16;
typedef __bf16 bf16x4 __attribute__((ext_vector_type(4)));
typedef __bf16 bf16x8 __attribute__((ext_vector_type(8)));
typedef float  f32x4  __attribute__((ext_vector_type(4)));

__device__ __forceinline__ bf16 f2b(float x){
  uint32_t u = __builtin_bit_cast(uint32_t, x);
  uint32_t r = (u + 0x7FFFu + ((u >> 16) & 1u)) >> 16;   // RNE
  return __builtin_bit_cast(bf16, (uint16_t)r);
}

// ---------------- cast f32 -> bf16 (vectorized) ----------------
__global__ __launch_bounds__(256) void castb_kernel(const float* __restrict__ in,
                                                    bf16* __restrict__ out, int n4){
  const int i = blockIdx.x*256 + threadIdx.x;
  if (i >= n4) return;
  const float4 v = ((const float4*)in)[i];
  bf16x4 u = { f2b(v.x), f2b(v.y), f2b(v.z), f2b(v.w) };
  *(bf16x4*)(out + (size_t)i*4) = u;
}

// ---------------- transpose+cast W[K][N] f32 -> Wt[N][K] bf16 ----------------
__global__ void transcast_kernel(const float* __restrict__ W, bf16* __restrict__ Wt,
                                 int K, int N){
  __shared__ float t[32][33];
  const int x = threadIdx.x, y = threadIdx.y;           // (32,8)
  const int n0 = blockIdx.x*32, k0 = blockIdx.y*32;
  #pragma unroll
  for (int r=0;r<4;r++) t[y+8*r][x] = W[(size_t)(k0+y+8*r)*N + n0+x];
  __syncthreads();
  #pragma unroll
  for (int r=0;r<4;r++) Wt[(size_t)(n0+y+8*r)*K + k0+x] = f2b(t[x][y+8*r]);
}

// ---------------- GEMM: C = A[M][K] * Bt[N][K]^T + bias ----------------
// 128x128 tile, 4 waves (2x2), each wave 64x64 = 4x4 fragments of 16x16x32 MFMA.
// LDS tiles [128][32] bf16 with 16B-slot XOR swizzle: slot ^= (row>>1)&3
// (keeps ds_read_b128 fragment reads at 2-way conflicts = free).
// OMODE: 0=f32, 1=bf16, 2=bf16+swish, 3=bf16 written V-transposed [b*1024+col][2048]
template<int OMODE>
__global__ __launch_bounds__(256) void gemm_bt_kernel(
    const bf16* __restrict__ A, const bf16* __restrict__ Bt,
    const float* __restrict__ bias, void* __restrict__ C,
    int M, int N, int K)
{
  __shared__ bf16 As[128*32];
  __shared__ bf16 Bs[128*32];
  const int tid = threadIdx.x;
  const int w = tid >> 6, lane = tid & 63;
  const int wr = w >> 1, wc = w & 1;
  const int g16 = lane >> 4, l16 = lane & 15;
  const int m0 = blockIdx.y*128, n0 = blockIdx.x*128;

  // staging: chunk c = tid -> row c>>2 (0..63), slot c&3; chunk tid+256 -> row+64
  const int ar = tid >> 2, asl = tid & 3;
  const bf16* gA = A  + (size_t)(m0+ar)*K + asl*8;
  const bf16* gB = Bt + (size_t)(n0+ar)*K + asl*8;
  const int sw0 = (ar>>1)&3;                       // ((ar+64)>>1)&3 == sw0
  const int la = ar*32      + ((asl ^ sw0)<<3);
  const int lb = (ar+64)*32 + ((asl ^ sw0)<<3);

  f32x4 acc[4][4];
  const f32x4 fz = {0.f,0.f,0.f,0.f};
  #pragma unroll
  for (int m=0;m<4;m++)
    #pragma unroll
    for (int n=0;n<4;n++) acc[m][n] = fz;

  bf16x8 ra0 = *(const bf16x8*)gA;
  bf16x8 ra1 = *(const bf16x8*)(gA + (size_t)64*K);
  bf16x8 rb0 = *(const bf16x8*)gB;
  bf16x8 rb1 = *(const bf16x8*)(gB + (size_t)64*K);

  for (int k0=0; k0<K; k0+=32){
    __syncthreads();                                // all waves done reading LDS
    *(bf16x8*)&As[la] = ra0;
    *(bf16x8*)&As[lb] = ra1;
    *(bf16x8*)&Bs[la] = rb0;
    *(bf16x8*)&Bs[lb] = rb1;
    __syncthreads();
    if (k0 + 32 < K){                               // prefetch next K-tile into regs
      ra0 = *(const bf16x8*)(gA + k0+32);
      ra1 = *(const bf16x8*)(gA + (size_t)64*K + k0+32);
      rb0 = *(const bf16x8*)(gB + k0+32);
      rb1 = *(const bf16x8*)(gB + (size_t)64*K + k0+32);
    }
    bf16x8 af[4], bfv[4];
    #pragma unroll
    for (int m=0;m<4;m++){
      const int r = wr*64 + m*16 + l16;
      af[m] = *(const bf16x8*)&As[r*32 + ((g16 ^ ((r>>1)&3))<<3)];
    }
    #pragma unroll
    for (int n=0;n<4;n++){
      const int r = wc*64 + n*16 + l16;
      bfv[n] = *(const bf16x8*)&Bs[r*32 + ((g16 ^ ((r>>1)&3))<<3)];
    }
    #pragma unroll
    for (int m=0;m<4;m++)
      #pragma unroll
      for (int n=0;n<4;n++)
        acc[m][n] = __builtin_amdgcn_mfma_f32_16x16x32_bf16(af[m], bfv[n], acc[m][n], 0, 0, 0);
  }

  // epilogue: D[i][j]: j = lane&15, i = 4*(lane>>4)+reg  [measured layout]
  const int cb = n0 + wc*64 + l16;
  #pragma unroll
  for (int n=0;n<4;n++){
    const int col = cb + n*16;
    const float bv = bias[col];
    #pragma unroll
    for (int m=0;m<4;m++){
      const int rbase = m0 + wr*64 + m*16 + g16*4;
      #pragma unroll
      for (int r=0;r<4;r++){
        float v = acc[m][n][r] + bv;
        const size_t row = (size_t)(rbase + r);
        if constexpr (OMODE==0){
          ((float*)C)[row*N + col] = v;
        } else if constexpr (OMODE==1){
          ((bf16*)C)[row*N + col] = f2b(v);
        } else if constexpr (OMODE==2){
          v = v / (1.f + __expf(-v));               // swish
          ((bf16*)C)[row*N + col] = f2b(v);
        } else {                                    // V transposed: [b*1024+col][2048]
          const size_t bq = row >> 11, s = row & 2047;
          ((bf16*)C)[(bq*1024 + (size_t)col)*2048 + s] = f2b(v);
        }
      }
    }
  }
}

// ---------------- flash attention ----------------
// grid (S/64, HEADS, B), 4 waves/block, each wave owns 16 q-rows.
// KV tile = 32. QK^T and PV via 16x16x32 MFMA; P goes through swizzled LDS
// to convert D-layout -> A-layout. V is pre-transposed (Vt[b*1024+h*64+d][s]).
__global__ __launch_bounds__(256) void attn_kernel(
    const bf16* __restrict__ Q, const bf16* __restrict__ Km,
    const bf16* __restrict__ Vt, const int* __restrict__ msk,
    bf16* __restrict__ O)
{
  const int tid = threadIdx.x;
  const int w = tid>>6, lane = tid&63;
  const int g16 = lane>>4, l16 = lane&15;
  const int b = blockIdx.z, h = blockIdx.y;
  const int q0 = blockIdx.x*64 + w*16;

  __shared__ bf16 plds[4][16*32];

  const bf16* qp = Q + (size_t)(b*2048 + q0 + l16)*1024 + h*64 + g16*8;
  const bf16x8 aq0 = *(const bf16x8*)qp;
  const bf16x8 aq1 = *(const bf16x8*)(qp + 32);
  const bf16* Kb = Km + (size_t)b*2048*1024 + h*64;
  const bf16* Vb = Vt + (size_t)(b*16 + h)*64*2048;
  const int* mb = msk + b*2048;

  float m_[4] = {-1e30f,-1e30f,-1e30f,-1e30f};
  float l_[4] = {0.f,0.f,0.f,0.f};
  const f32x4 fz = {0.f,0.f,0.f,0.f};
  f32x4 xa[4];
  #pragma unroll
  for (int i=0;i<4;i++) xa[i] = fz;

  for (int kv=0; kv<2048; kv+=32){
    const bf16* kp = Kb + (size_t)(kv + l16)*1024 + g16*8;
    f32x4 s0 = fz, s1 = fz;
    s0 = __builtin_amdgcn_mfma_f32_16x16x32_bf16(aq0, *(const bf16x8*)kp,            s0, 0,0,0);
    s0 = __builtin_amdgcn_mfma_f32_16x16x32_bf16(aq1, *(const bf16x8*)(kp+32),       s0, 0,0,0);
    s1 = __builtin_amdgcn_mfma_f32_16x16x32_bf16(aq0, *(const bf16x8*)(kp+16*1024),  s1, 0,0,0);
    s1 = __builtin_amdgcn_mfma_f32_16x16x32_bf16(aq1, *(const bf16x8*)(kp+16*1024+32), s1, 0,0,0);
    const bool z0 = (mb[kv + l16] == 0);
    const bool z1 = (mb[kv + 16 + l16] == 0);
    #pragma unroll
    for (int r=0;r<4;r++){
      float v0 = z0 ? -1e10f : s0[r]*0.125f;        // /sqrt(64)
      float v1 = z1 ? -1e10f : s1[r]*0.125f;
      float t = fmaxf(v0, v1);
      t = fmaxf(t, __shfl_xor(t, 1, 64));
      t = fmaxf(t, __shfl_xor(t, 2, 64));
      t = fmaxf(t, __shfl_xor(t, 4, 64));
      t = fmaxf(t, __shfl_xor(t, 8, 64));
      const float mn = fmaxf(m_[r], t);
      const float sc = __expf(m_[r] - mn);
      const float p0 = __expf(v0 - mn);
      const float p1 = __expf(v1 - mn);
      float rs = p0 + p1;
      rs += __shfl_xor(rs, 1, 64);
      rs += __shfl_xor(rs, 2, 64);
      rs += __shfl_xor(rs, 4, 64);
      rs += __shfl_xor(rs, 8, 64);
      l_[r] = l_[r]*sc + rs;
      m_[r] = mn;
      xa[0][r]*=sc; xa[1][r]*=sc; xa[2][r]*=sc; xa[3][r]*=sc;
      const int row = g16*4 + r;
      const int sw = (row>>1)&3;
      plds[w][row*32 + ((( l16>>3     )^sw)<<3) + (l16&7)] = f2b(p0);
      plds[w][row*32 + ((((l16>>3)+2  )^sw)<<3) + (l16&7)] = f2b(p1);
    }
    // same-wave DS ops are in-order; compiler inserts lgkmcnt for the read.
    const bf16x8 pa = *(const bf16x8*)&plds[w][l16*32 + ((g16 ^ ((l16>>1)&3))<<3)];
    #pragma unroll
    for (int jd=0;jd<4;jd++){
      const bf16x8 vb = *(const bf16x8*)(Vb + (size_t)(jd*16 + l16)*2048 + kv + g16*8);
      xa[jd] = __builtin_amdgcn_mfma_f32_16x16x32_bf16(pa, vb, xa[jd], 0,0,0);
    }
  }
  #pragma unroll
  for (int jd=0;jd<4;jd++){
    #pragma unroll
    for (int r=0;r<4;r++){
      const size_t row = (size_t)(b*2048 + q0 + g16*4 + r);
      O[row*1024 + h*64 + jd*16 + l16] = f2b(xa[jd][r] / l_[r]);
    }
  }
}

// ---------------- residual + layernorm (row = 1024) ----------------
__global__ __launch_bounds__(256) void addln_kernel(
    const float* __restrict__ X, const float* __restrict__ R,
    const float* __restrict__ g, const float* __restrict__ be,
    float* __restrict__ of, bf16* __restrict__ ob)
{
  const int row = blockIdx.x, tid = threadIdx.x;
  const float4 vx = ((const float4*)(X + (size_t)row*1024))[tid];
  const float4 vr = ((const float4*)(R + (size_t)row*1024))[tid];
  const float a0 = vx.x+vr.x, a1 = vx.y+vr.y, a2 = vx.z+vr.z, a3 = vx.w+vr.w;
  float s = a0+a1+a2+a3;
  float q = a0*a0 + a1*a1 + a2*a2 + a3*a3;
  #pragma unroll
  for (int off=1; off<64; off<<=1){
    s += __shfl_xor(s, off, 64);
    q += __shfl_xor(q, off, 64);
  }
  __shared__ float sb[8];
  if ((tid&63)==0){ sb[tid>>6] = s; sb[4+(tid>>6)] = q; }
  __syncthreads();
  s = sb[0]+sb[1]+sb[2]+sb[3];
  q = sb[4]+sb[5]+sb[6]+sb[7];
  const float mu = s*(1.f/1024.f);
  const float rs = rsqrtf(q*(1.f/1024.f) - mu*mu + 1e-5f);
  const float4 gg = ((const float4*)g)[tid];
  const float4 bb = ((const float4*)be)[tid];
  const float o0 = (a0-mu)*rs*gg.x + bb.x;
  const float o1 = (a1-mu)*rs*gg.y + bb.y;
  const float o2 = (a2-mu)*rs*gg.z + bb.z;
  const float o3 = (a3-mu)*rs*gg.w + bb.w;
  float4 o; o.x=o0; o.y=o1; o.z=o2; o.w=o3;
  ((float4*)(of + (size_t)row*1024))[tid] = o;
  if (ob){
    bf16x4 u = { f2b(o0), f2b(o1), f2b(o2), f2b(o3) };
    *(bf16x4*)(ob + (size_t)row*1024 + tid*4) = u;
  }
}

// ---------------- launch ----------------
extern "C" void kernel_launch(void* const* d_in, const int* in_sizes, int n_in,
                              void* d_out, int out_size, void* d_ws, size_t ws_size,
                              hipStream_t stream)
{
  const float* src  = (const float*)d_in[0];
  const int*   mask = (const int*)  d_in[1];
  const float* Wq = (const float*)d_in[2];  const float* bq = (const float*)d_in[3];
  const float* Wk = (const float*)d_in[4];  const float* bk = (const float*)d_in[5];
  const float* Wv = (const float*)d_in[6];  const float* bv = (const float*)d_in[7];
  const float* Wo = (const float*)d_in[8];  const float* bo = (const float*)d_in[9];
  const float* W1 = (const float*)d_in[10]; const float* b1 = (const float*)d_in[11];
  const float* W2 = (const float*)d_in[12]; const float* b2 = (const float*)d_in[13];
  const float* g1 = (const float*)d_in[14]; const float* be1 = (const float*)d_in[15];
  const float* g2 = (const float*)d_in[16]; const float* be2 = (const float*)d_in[17];

  char* ws = (char*)d_ws;
  const size_t MB = 1u<<20;
  // region map (peak 168 MB), with deliberate reuse once producers/consumers retire:
  bf16* srcb = (bf16*)(ws + 0*MB);     // 16 MB  [dead after QKV gemms]
  bf16* Wqt  = (bf16*)(ws + 16*MB);    // 2 MB
  bf16* Wkt  = (bf16*)(ws + 18*MB);
  bf16* Wvt  = (bf16*)(ws + 20*MB);
  bf16* Wot  = (bf16*)(ws + 22*MB);
  bf16* W1t  = (bf16*)(ws + 24*MB);    // 8 MB
  bf16* W2t  = (bf16*)(ws + 32*MB);    // 8 MB
  bf16* Qb   = (bf16*)(ws + 40*MB);    // 16 MB [dead after attn]
  bf16* Kb   = (bf16*)(ws + 56*MB);    // 16 MB [dead after attn]
  bf16* Vtb  = (bf16*)(ws + 72*MB);    // 16 MB [dead after attn]
  bf16* AO   = (bf16*)(ws + 88*MB);    // 16 MB [dead after O-proj]
  float* X1  = (float*)(ws + 40*MB);   // 32 MB over Qb+Kb
  float* S1F = (float*)(ws + 72*MB);   // 32 MB over Vtb+AO
  bf16*  S1B = (bf16*)(ws + 0*MB);     // 16 MB over srcb
  bf16*  H1  = (bf16*)(ws + 104*MB);   // 64 MB
  float* F2  = (float*)(ws + 40*MB);   // 32 MB over X1 (dead after LN1)

  // casts + weight transposes
  castb_kernel<<<8192, 256, 0, stream>>>(src, srcb, 8192*1024/4);
  transcast_kernel<<<dim3(32,32),  dim3(32,8), 0, stream>>>(Wq, Wqt, 1024, 1024);
  transcast_kernel<<<dim3(32,32),  dim3(32,8), 0, stream>>>(Wk, Wkt, 1024, 1024);
  transcast_kernel<<<dim3(32,32),  dim3(32,8), 0, stream>>>(Wv, Wvt, 1024, 1024);
  transcast_kernel<<<dim3(32,32),  dim3(32,8), 0, stream>>>(Wo, Wot, 1024, 1024);
  transcast_kernel<<<dim3(128,32), dim3(32,8), 0, stream>>>(W1, W1t, 1024, 4096);
  transcast_kernel<<<dim3(32,128), dim3(32,8), 0, stream>>>(W2, W2t, 4096, 1024);

  // QKV projections
  gemm_bt_kernel<1><<<dim3(8,64),  256, 0, stream>>>(srcb, Wqt, bq, Qb,  8192, 1024, 1024);
  gemm_bt_kernel<1><<<dim3(8,64),  256, 0, stream>>>(srcb, Wkt, bk, Kb,  8192, 1024, 1024);
  gemm_bt_kernel<3><<<dim3(8,64),  256, 0, stream>>>(srcb, Wvt, bv, Vtb, 8192, 1024, 1024);

  // attention
  attn_kernel<<<dim3(32,16,4), 256, 0, stream>>>(Qb, Kb, Vtb, mask, AO);

  // output projection + LN1
  gemm_bt_kernel<0><<<dim3(8,64),  256, 0, stream>>>(AO, Wot, bo, X1, 8192, 1024, 1024);
  addln_kernel<<<8192, 256, 0, stream>>>(X1, src, g1, be1, S1F, S1B);

  // FFN (swish) + LN2 -> d_out
  gemm_bt_kernel<2><<<dim3(32,64), 256, 0, stream>>>(S1B, W1t, b1, H1, 8192, 4096, 1024);
  gemm_bt_kernel<0><<<dim3(8,64),  256, 0, stream>>>(H1,  W2t, b2, F2, 8192, 1024, 4096);
  addln_kernel<<<8192, 256, 0, stream>>>(F2, S1F, g2, be2, (float*)d_out, (bf16*)nullptr);
}